// Round 7
// baseline (428.072 us; speedup 1.0000x reference)
//
#include <hip/hip_runtime.h>
#include <hip/hip_bf16.h>
#include <stdint.h>

#define NB 4
#define NK 64
#define NL 128
#define ND 768
#define NBK (NB*NK)        // 256
#define NROW (NBK*NL)      // 32768
#define LD2 (NL*ND)        // 98304
#define EPSF 1e-8f
#define THETA 2e-3f        // candidate window on dot*einv scale
#define CAP 16384          // candidate list capacity (expect ~300)
#define TSTR 40            // LDS row stride: 80B = 5 slots, odd mod 8 -> 2-way (free), 16B-aligned

typedef __bf16 bf16x8 __attribute__((ext_vector_type(8)));
typedef float  f32x4  __attribute__((ext_vector_type(4)));

// Row space r in [0, 2*NROW): [0,NROW) = ctx rows, [NROW,2*NROW) = ent rows.
__device__ __forceinline__ int row_off(int r) {
  if (r < NROW) return r*ND + (r >> 7)*LD2;
  int r2 = r - NROW;
  return r2*ND + (r2 >> 7)*LD2 + LD2;
}

// ---------------- K0: w1 -> w1t (row layout) + w1f (fragment-major) --------
// w1f[((nt*24+ks)*64 + lane)*8 + j] = w1[ks*32+quad*8+j][nt*16+eloc] — the
// exact MFMA B-frag per (out-tile nt, kstep ks); consumers read 1KB coalesced.
// (validated in rounds 4-5). Also zero-inits fixup state.
__global__ __launch_bounds__(256) void k0_w1t(const float* __restrict__ w1,
                                              __bf16* __restrict__ w1t,
                                              __bf16* __restrict__ w1f,
                                              unsigned long long* __restrict__ amax2,
                                              unsigned* __restrict__ cntg) {
  __shared__ float tile[64][68];               // [k][e], +4 pad
  int idx = blockIdx.x*256 + threadIdx.x;
  if (idx < NROW) amax2[idx] = 0ull;
  if (idx == 0) *cntg = 0u;
  int kb = (blockIdx.x / 12) * 64, eb = (blockIdx.x % 12) * 64;
  int t = threadIdx.x;
  int r = t >> 2, c0 = (t & 3) * 16;
  #pragma unroll
  for (int j = 0; j < 4; j++) {
    f32x4 v = *(const f32x4*)(w1 + (kb + r)*ND + eb + c0 + j*4);
    *(f32x4*)&tile[r][c0 + j*4] = v;
  }
  __syncthreads();
  int e = t & 63, gi = t >> 6;
  int eg = eb + e;
  #pragma unroll
  for (int g2 = 0; g2 < 2; g2++) {
    int g = gi*2 + g2;
    bf16x8 o;
    #pragma unroll
    for (int j = 0; j < 8; j++) o[j] = (__bf16)tile[g*8 + j][e];
    int G = (kb >> 3) + (g ^ (eg & 7));        // XOR layout for k3e frag reads
    *(bf16x8*)(w1t + eg*ND + G*8) = o;
  }
  // fragment-major pack: 4 nt-tiles x 2 ks-steps = 8 frags x 64 lanes
  #pragma unroll
  for (int rr = 0; rr < 2; rr++) {
    int task = t + rr*256;
    int fi = task >> 6, l = task & 63;
    int nt_loc = fi & 3, ks_loc = fi >> 2;
    int quad = l >> 4, eloc = l & 15;
    bf16x8 o;
    #pragma unroll
    for (int j = 0; j < 8; j++)
      o[j] = (__bf16)tile[ks_loc*32 + quad*8 + j][nt_loc*16 + eloc];
    int nt = (eb >> 4) + nt_loc, ks = (kb >> 5) + ks_loc;
    *(bf16x8*)(w1f + (size_t)((nt*24 + ks)*64 + l)*8) = o;
  }
}

// split f32x4 into truncated-bf16 hi and exact-remainder lo (bf16); sum sq.
__device__ __forceinline__ void cvt4(f32x4 v, unsigned& hp0, unsigned& hp1,
                                     unsigned& lp0, unsigned& lp1, float& sq) {
  unsigned u0 = __float_as_uint(v[0]), u1 = __float_as_uint(v[1]);
  unsigned u2 = __float_as_uint(v[2]), u3 = __float_as_uint(v[3]);
  hp0 = (u1 & 0xffff0000u) | (u0 >> 16);
  hp1 = (u3 & 0xffff0000u) | (u2 >> 16);
  float l0 = v[0] - __uint_as_float(u0 & 0xffff0000u);   // exact (Sterbenz)
  float l1 = v[1] - __uint_as_float(u1 & 0xffff0000u);
  float l2 = v[2] - __uint_as_float(u2 & 0xffff0000u);
  float l3 = v[3] - __uint_as_float(u3 & 0xffff0000u);
  lp0 = (__float_as_uint(l1) & 0xffff0000u) | (__float_as_uint(l0) >> 16);
  lp1 = (__float_as_uint(l3) & 0xffff0000u) | (__float_as_uint(l2) >> 16);
  sq += v[0]*v[0] + v[1]*v[1] + v[2]*v[2] + v[3]*v[3];
}

// ---------------- K2M: fused cosine screen + ctx-half MLP ------------------
// Block = (bk, half): 64 ctx rows x 128 ent. 512 thr = 8 waves.
// Staging: t<256 stage ent rows (srow=t>>1, khalf t&1); t in [256,384) stage
// ctx rows. Screen: waves 0-3, EXACTLY the validated v2 geometry (wave w owns
// ctx rows w*16..+15, all 128 ent cols, split-bf16 3-MFMA accumulate) and the
// validated argmax/THETA-candidate epilogue. MLP (ctx half): ALL 8 waves;
// wave w owns output tiles nt = w*6..w*6+5 for all 64 rows: acc[6][4] in
// AGPRs; per kt, A = the SAME hi/lo LDS tiles the screen staged ((ah+al)*w1
// = 16-bit-precise A, better than k3's single RNE bf16), B = w1f frag-major
// (1KB coalesced L2 reads, one read per block per frag instead of k3's
// per-wave). rinv folded at output (validated r2). Removes k3's second HBM
// read of ctx (100 MB) and its per-wave w1 LDS streaming.
__global__ __launch_bounds__(512, 2) void k2m_fused(
    const float* __restrict__ ctxall, float* __restrict__ norm,
    int* __restrict__ amax, unsigned* __restrict__ cntg,
    unsigned* __restrict__ list, const __bf16* __restrict__ w1f,
    const float* __restrict__ b1, const float* __restrict__ w2,
    float* __restrict__ val) {
  __shared__ alignas(16) __bf16 Bh[2][128*TSTR], Bl[2][128*TSTR]; // ent hi/lo (40 KB)
  __shared__ alignas(16) __bf16 Ah[2][64*TSTR],  Al[2][64*TSTR];  // ctx hi/lo (20 KB)
  __shared__ float einv_s[128];
  __shared__ float cinv_s[64];
  __shared__ float red[8][64];
  int bk = blockIdx.x & 255, half = blockIdx.x >> 8;   // pair 256 apart -> same XCD
  int t = threadIdx.x;
  int w = t >> 6, lane = t & 63, quad = lane >> 4, eloc = lane & 15;
  bool stE = (t < 256);                // ent stagers (= screen waves 0-3)
  bool stC = (t >= 256 && t < 384);    // ctx stagers (waves 4-5)
  int srow  = (t >> 1) & 127;          // ent row for stE
  int csrow = (t >> 1) & 63;           // ctx row for stC ((t-256)>>1)
  int kh = (t & 1) * 16;
  const float* bsrc = ctxall + bk*2*LD2 + LD2 + srow*ND + kh;
  const float* asrc = ctxall + bk*2*LD2 + (half*64 + csrow)*ND + kh;

  f32x4 pa[4], pb[4];
  if (stE) {
    #pragma unroll
    for (int i = 0; i < 4; i++) pb[i] = *(const f32x4*)(bsrc + i*4);
  } else if (stC) {
    #pragma unroll
    for (int i = 0; i < 4; i++) pa[i] = *(const f32x4*)(asrc + i*4);
  }
  float sqa = 0.f, sqb = 0.f;
  f32x4 accs[8];
  #pragma unroll
  for (int ct = 0; ct < 8; ct++) accs[ct] = (f32x4){0,0,0,0};
  f32x4 accm[6][4];
  #pragma unroll
  for (int i = 0; i < 6; i++)
    #pragma unroll
    for (int rt = 0; rt < 4; rt++) accm[i][rt] = (f32x4){0,0,0,0};
  float b1v[6], w2v[6];
  #pragma unroll
  for (int i = 0; i < 6; i++) {
    int c = (w*6 + i)*16 + eloc;
    b1v[i] = b1[c];
    w2v[i] = w2[c];
  }

  int p = 0;
  for (int kt = 0; kt < 24; kt++) {
    unsigned h0,h1,h2,h3, l0,l1,l2,l3;
    if (stE) {
      cvt4(pb[0], h0, h1, l0, l1, sqb);
      cvt4(pb[1], h2, h3, l2, l3, sqb);
      *(uint4*)&Bh[p][srow*TSTR + kh] = make_uint4(h0,h1,h2,h3);
      *(uint4*)&Bl[p][srow*TSTR + kh] = make_uint4(l0,l1,l2,l3);
      cvt4(pb[2], h0, h1, l0, l1, sqb);
      cvt4(pb[3], h2, h3, l2, l3, sqb);
      *((uint4*)&Bh[p][srow*TSTR + kh] + 1) = make_uint4(h0,h1,h2,h3);
      *((uint4*)&Bl[p][srow*TSTR + kh] + 1) = make_uint4(l0,l1,l2,l3);
    } else if (stC) {
      cvt4(pa[0], h0, h1, l0, l1, sqa);
      cvt4(pa[1], h2, h3, l2, l3, sqa);
      *(uint4*)&Ah[p][csrow*TSTR + kh] = make_uint4(h0,h1,h2,h3);
      *(uint4*)&Al[p][csrow*TSTR + kh] = make_uint4(l0,l1,l2,l3);
      cvt4(pa[2], h0, h1, l0, l1, sqa);
      cvt4(pa[3], h2, h3, l2, l3, sqa);
      *((uint4*)&Ah[p][csrow*TSTR + kh] + 1) = make_uint4(h0,h1,h2,h3);
      *((uint4*)&Al[p][csrow*TSTR + kh] + 1) = make_uint4(l0,l1,l2,l3);
    }
    __syncthreads();
    // MLP B-frags for this kt: coalesced 1KB reads from L2-hot w1f
    bf16x8 bf[6];
    #pragma unroll
    for (int i = 0; i < 6; i++)
      bf[i] = *(const bf16x8*)(w1f + (size_t)(((w*6 + i)*24 + kt)*64 + lane)*8);
    if (kt < 23) {                             // prefetch next kt over compute
      if (stE) {
        const float* b2p = bsrc + (kt+1)*32;
        #pragma unroll
        for (int i = 0; i < 4; i++) pb[i] = *(const f32x4*)(b2p + i*4);
      } else if (stC) {
        const float* a2p = asrc + (kt+1)*32;
        #pragma unroll
        for (int i = 0; i < 4; i++) pa[i] = *(const f32x4*)(a2p + i*4);
      }
    }
    // screen (waves 0-3): v2-validated 3-MFMA split accumulate
    if (t < 256) {
      bf16x8 ah = *(const bf16x8*)&Ah[p][(w*16+eloc)*TSTR + quad*8];
      bf16x8 al = *(const bf16x8*)&Al[p][(w*16+eloc)*TSTR + quad*8];
      #pragma unroll
      for (int ct = 0; ct < 8; ct++) {
        bf16x8 bh = *(const bf16x8*)&Bh[p][(ct*16+eloc)*TSTR + quad*8];
        bf16x8 bl = *(const bf16x8*)&Bl[p][(ct*16+eloc)*TSTR + quad*8];
        accs[ct] = __builtin_amdgcn_mfma_f32_16x16x32_bf16(al, bh, accs[ct], 0, 0, 0);
        accs[ct] = __builtin_amdgcn_mfma_f32_16x16x32_bf16(ah, bl, accs[ct], 0, 0, 0);
        accs[ct] = __builtin_amdgcn_mfma_f32_16x16x32_bf16(ah, bh, accs[ct], 0, 0, 0);
      }
    }
    // ctx-MLP (all 8 waves): (ah+al) x w1f, 2 MFMA per (nt, row-tile)
    #pragma unroll
    for (int rt = 0; rt < 4; rt++) {
      bf16x8 mah = *(const bf16x8*)&Ah[p][(rt*16+eloc)*TSTR + quad*8];
      bf16x8 mal = *(const bf16x8*)&Al[p][(rt*16+eloc)*TSTR + quad*8];
      #pragma unroll
      for (int i = 0; i < 6; i++) {
        accm[i][rt] = __builtin_amdgcn_mfma_f32_16x16x32_bf16(mal, bf[i], accm[i][rt], 0, 0, 0);
        accm[i][rt] = __builtin_amdgcn_mfma_f32_16x16x32_bf16(mah, bf[i], accm[i][rt], 0, 0, 0);
      }
    }
    p ^= 1;
  }

  // norms (pairs (t, t^1) hold the two k-halves of one staged row)
  if (stE) {
    float stb = sqb + __shfl_xor(sqb, 1);
    if ((t & 1) == 0) {
      float n = sqrtf(stb);
      norm[NROW + bk*NL + srow] = n;           // both halves write same (benign)
      einv_s[srow] = 1.0f / n;
    }
  } else if (stC) {
    float sta = sqa + __shfl_xor(sqa, 1);
    if ((t & 1) == 0) {
      float n = sqrtf(sta);
      norm[bk*NL + half*64 + csrow] = n;
      cinv_s[csrow] = 1.0f / n;
    }
  }
  __syncthreads();

  // screen epilogue (waves 0-3): v2-validated argmax + THETA candidates
  if (t < 256) {
    #pragma unroll
    for (int rr = 0; rr < 4; rr++) {
      float sc[8];
      float best = -3.0e38f; int bcol = 0;
      #pragma unroll
      for (int ct = 0; ct < 8; ct++) {
        sc[ct] = accs[ct][rr] * einv_s[ct*16 + eloc];
        int col = ct*16 + eloc;
        if (sc[ct] > best) { best = sc[ct]; bcol = col; }
      }
      #pragma unroll
      for (int m = 1; m < 16; m <<= 1) {
        float ov = __shfl_xor(best, m);
        int   oc = __shfl_xor(bcol, m);
        if (ov > best || (ov == best && oc < bcol)) { best = ov; bcol = oc; }
      }
      int grow = bk*NL + half*64 + w*16 + quad*4 + rr;
      if (eloc == 0) amax[grow] = bcol;
      int cnt = 0;
      #pragma unroll
      for (int ct = 0; ct < 8; ct++) cnt += (sc[ct] >= best - THETA) ? 1 : 0;
      #pragma unroll
      for (int m = 1; m < 16; m <<= 1) cnt += __shfl_xor(cnt, m);
      if (cnt >= 2) {
        #pragma unroll
        for (int ct = 0; ct < 8; ct++) {
          if (sc[ct] >= best - THETA) {
            unsigned idx = atomicAdd(cntg, 1u);
            if (idx < CAP) list[idx] = ((unsigned)grow << 7) | (unsigned)(ct*16 + eloc);
          }
        }
      }
    }
  }

  // MLP epilogue (all waves): h = acc*rinv, relu, dot w2; reduce over eloc
  // lanes (this wave's 6 nt), then cross-wave sum via LDS.
  #pragma unroll
  for (int rt = 0; rt < 4; rt++) {
    float pr[4];
    #pragma unroll
    for (int rr = 0; rr < 4; rr++) {
      float ci = cinv_s[rt*16 + quad*4 + rr];
      float s = 0.f;
      #pragma unroll
      for (int i = 0; i < 6; i++)
        s += fmaxf(accm[i][rt][rr]*ci + b1v[i], 0.f) * w2v[i];
      pr[rr] = s;
    }
    #pragma unroll
    for (int m = 1; m < 16; m <<= 1)
      #pragma unroll
      for (int rr = 0; rr < 4; rr++) pr[rr] += __shfl_xor(pr[rr], m);
    if (eloc == 0) {
      #pragma unroll
      for (int rr = 0; rr < 4; rr++) red[w][rt*16 + quad*4 + rr] = pr[rr];
    }
  }
  __syncthreads();
  if (t < 64) {
    float s = 0.f;
    #pragma unroll
    for (int w8 = 0; w8 < 8; w8++) s += red[w8][t];
    val[bk*NL + half*64 + t] = s;
  }
}

// ---------------- K2b: exact f32 rescore of near-tie candidates ------------
__global__ __launch_bounds__(256) void k2b_rescore(
    const float* __restrict__ ctxall, const float* __restrict__ norm,
    const unsigned* __restrict__ cntg, const unsigned* __restrict__ list,
    unsigned long long* __restrict__ amax2) {
  unsigned n = *cntg; if (n > CAP) n = CAP;
  int lane = threadIdx.x & 63;
  unsigned wv = blockIdx.x*4 + (threadIdx.x >> 6);
  for (unsigned e = wv; e < n; e += 256) {
    unsigned ent = list[e];
    int row = (int)(ent >> 7), col = (int)(ent & 127);
    int bk = row >> 7;
    const float* a = ctxall + row_off(row);
    const float* b = ctxall + bk*2*LD2 + LD2 + col*ND;
    float d = 0.f;
    #pragma unroll
    for (int i = 0; i < 3; i++) {
      f32x4 va = *(const f32x4*)(a + lane*12 + i*4);
      f32x4 vb = *(const f32x4*)(b + lane*12 + i*4);
      d += va[0]*vb[0] + va[1]*vb[1] + va[2]*vb[2] + va[3]*vb[3];
    }
    #pragma unroll
    for (int m = 1; m < 64; m <<= 1) d += __shfl_xor(d, m);
    if (lane == 0) {
      float cn = norm[row], en = norm[NROW + bk*NL + col];
      float s = d / (cn*en + EPSF);
      unsigned su = __float_as_uint(s);
      unsigned ord = (su & 0x80000000u) ? ~su : (su | 0x80000000u);
      unsigned long long key = ((unsigned long long)ord << 32) | (unsigned)(127 - col);
      atomicMax(&amax2[row], key);
    }
  }
}

// ---------------- K3e: fused MLP for ENT rows only (round-0 k3 + rb0) ------
// Proven fastest MLP structure (f32-source + cvt, afrag in AGPRs). Grid
// halved: ctx half now computed inside k2m_fused.
__global__ __launch_bounds__(256, 2) void k3_mlp(
    const float* __restrict__ ctxall, const float* __restrict__ norm,
    const __bf16* __restrict__ w1t, const float* __restrict__ b1,
    const float* __restrict__ w2, float* __restrict__ val, int rb0) {
  __shared__ alignas(16) __bf16 btile[2][16*768];   // 2 x 24 KB w1t tiles
  int tid = threadIdx.x;
  int wave = tid >> 6, lane = tid & 63;
  int quad = lane >> 4, eloc = lane & 15;
  int rbase = rb0 + blockIdx.x*128 + wave*32;

  #pragma unroll
  for (int i = 0; i < 6; i++) {
    __builtin_amdgcn_global_load_lds(
      (const __attribute__((address_space(1))) unsigned int*)(w1t + (i*256 + tid)*8),
      (__attribute__((address_space(3))) unsigned int*)(&btile[0][0] + (i*256 + tid)*8),
      16, 0, 0);
  }

  bf16x8 afrag[2][24];
  #pragma unroll
  for (int s = 0; s < 2; s++) {
    int r = rbase + s*16 + eloc;
    const float* src = ctxall + row_off(r);
    float rinv = 1.0f / norm[r];
    #pragma unroll
    for (int ks = 0; ks < 24; ks++) {
      const float* sp = src + ks*32 + quad*8;
      f32x4 v0 = *(const f32x4*)sp;
      f32x4 v1 = *(const f32x4*)(sp + 4);
      bf16x8 a;
      a[0] = (__bf16)(v0[0]*rinv); a[1] = (__bf16)(v0[1]*rinv);
      a[2] = (__bf16)(v0[2]*rinv); a[3] = (__bf16)(v0[3]*rinv);
      a[4] = (__bf16)(v1[0]*rinv); a[5] = (__bf16)(v1[1]*rinv);
      a[6] = (__bf16)(v1[2]*rinv); a[7] = (__bf16)(v1[3]*rinv);
      afrag[s][ks] = a;
    }
  }

  float oacc[2][4] = {{0,0,0,0},{0,0,0,0}};
  int p = 0;
  for (int nt = 0; nt < 48; nt++) {
    __syncthreads();
    if (nt < 47) {
      const __bf16* gsrc = w1t + (nt+1)*16*ND;
      #pragma unroll
      for (int i = 0; i < 6; i++) {
        __builtin_amdgcn_global_load_lds(
          (const __attribute__((address_space(1))) unsigned int*)(gsrc + (i*256 + tid)*8),
          (__attribute__((address_space(3))) unsigned int*)(&btile[p^1][0] + (i*256 + tid)*8),
          16, 0, 0);
      }
    }
    f32x4 h0 = {0,0,0,0}, h1 = {0,0,0,0};
    #pragma unroll
    for (int ks = 0; ks < 24; ks++) {
      int g = ks*4 + quad;
      bf16x8 bfrag = *(const bf16x8*)(&btile[p][0] + eloc*ND + ((g ^ (eloc & 7))*8));
      h0 = __builtin_amdgcn_mfma_f32_16x16x32_bf16(afrag[0][ks], bfrag, h0, 0, 0, 0);
      h1 = __builtin_amdgcn_mfma_f32_16x16x32_bf16(afrag[1][ks], bfrag, h1, 0, 0, 0);
    }
    float b1v = b1[nt*16 + eloc];
    float w2v = w2[nt*16 + eloc];
    #pragma unroll
    for (int rr = 0; rr < 4; rr++) {
      oacc[0][rr] += fmaxf(h0[rr] + b1v, 0.f) * w2v;
      oacc[1][rr] += fmaxf(h1[rr] + b1v, 0.f) * w2v;
    }
    p ^= 1;
  }
  #pragma unroll
  for (int m = 1; m < 16; m <<= 1)
    #pragma unroll
    for (int s = 0; s < 2; s++)
      #pragma unroll
      for (int rr = 0; rr < 4; rr++)
        oacc[s][rr] += __shfl_xor(oacc[s][rr], m);
  if (eloc == 0) {
    #pragma unroll
    for (int s = 0; s < 2; s++)
      #pragma unroll
      for (int rr = 0; rr < 4; rr++)
        val[rbase + s*16 + quad*4 + rr] = oacc[s][rr];
  }
}

// ---------------- K4: gather-add final output (with fixup override) --------
__global__ void k4_out(const float* __restrict__ val, const int* __restrict__ amax,
                       const unsigned long long* __restrict__ amax2,
                       const float* __restrict__ b2, float* __restrict__ out) {
  int i = blockIdx.x*256 + threadIdx.x;      // < NROW
  int bk = i >> 7;
  unsigned long long k = amax2[i];
  int a = k ? (127 - (int)(k & 127ull)) : amax[i];
  out[i] = val[i] + val[NROW + bk*NL + a] + 2.0f*b2[0];
}

extern "C" void kernel_launch(void* const* d_in, const int* in_sizes, int n_in,
                              void* d_out, int out_size, void* d_ws, size_t ws_size,
                              hipStream_t stream) {
  const float* ctxall = (const float*)d_in[0];
  const float* w1 = (const float*)d_in[1];
  const float* b1 = (const float*)d_in[2];
  const float* w2 = (const float*)d_in[3];
  const float* b2 = (const float*)d_in[4];
  float* out = (float*)d_out;

  char* ws = (char*)d_ws;
  float*    norm = (float*)ws;                        // [0, 262144)
  int*      amax = (int*)(ws + 262144);               // [262144, 393216)
  float*    val  = (float*)(ws + 393216);             // [393216, 655360)
  __bf16*   w1t  = (__bf16*)(ws + 655360);            // [655360, 1835008)
  unsigned long long* amax2 = (unsigned long long*)(ws + 1835008);  // 256 KB
  unsigned* cntg = (unsigned*)(ws + 2097152);         // 4 B
  unsigned* list = (unsigned*)(ws + 2097156);         // 64 KB
  __bf16*   w1f  = (__bf16*)(ws + 2228224);           // 1.15 MB frag-major w1

  hipLaunchKernelGGL(k0_w1t,     dim3(144),      dim3(256), 0, stream, w1, w1t, w1f, amax2, cntg);
  hipLaunchKernelGGL(k2m_fused,  dim3(2*NBK),    dim3(512), 0, stream, ctxall, norm, amax, cntg, list, w1f, b1, w2, val);
  hipLaunchKernelGGL(k2b_rescore,dim3(64),       dim3(256), 0, stream, ctxall, norm, cntg, list, amax2);
  hipLaunchKernelGGL(k3_mlp,     dim3(NROW/128), dim3(256), 0, stream, ctxall, norm, w1t, b1, w2, val, NROW);
  hipLaunchKernelGGL(k4_out,     dim3(NROW/256), dim3(256), 0, stream, val, amax, amax2, b2, out);
}

// Round 8
// 393.313 us; speedup vs baseline: 1.0884x; 1.0884x over previous
//
#include <hip/hip_runtime.h>
#include <hip/hip_bf16.h>
#include <stdint.h>

#define NB 4
#define NK 64
#define NL 128
#define ND 768
#define NBK (NB*NK)        // 256
#define NROW (NBK*NL)      // 32768
#define LD2 (NL*ND)        // 98304
#define EPSF 1e-8f
#define THETA 2e-3f        // candidate window on dot*einv scale (~75 sigma of split-bf16 error)
#define CAP 16384          // candidate list capacity (expect ~300)
#define BTS 56             // B-tile row stride: 112B = 7 slots, gcd(7,8)=1 -> 2-way (free), 16B-aligned

typedef __bf16 bf16x8 __attribute__((ext_vector_type(8)));
typedef float  f32x4  __attribute__((ext_vector_type(4)));

// Row space r in [0, 2*NROW): [0,NROW) = ctx rows (bk=r>>7, l=r&127),
// [NROW,2*NROW) = ent rows. Returns float offset into context tensor.
__device__ __forceinline__ int row_off(int r) {
  if (r < NROW) return r*ND + (r >> 7)*LD2;
  int r2 = r - NROW;
  return r2*ND + (r2 >> 7)*LD2 + LD2;
}

// ---------------- K0: w1 -> w1t transpose + zero-init of fixup state -------
__global__ __launch_bounds__(256) void k0_w1t(const float* __restrict__ w1,
                                              __bf16* __restrict__ w1t,
                                              unsigned long long* __restrict__ amax2,
                                              unsigned* __restrict__ cntg) {
  __shared__ float tile[64][68];               // [k][e], +4 pad
  int idx = blockIdx.x*256 + threadIdx.x;
  if (idx < NROW) amax2[idx] = 0ull;           // fixup keys zeroed every launch
  if (idx == 0) *cntg = 0u;
  int kb = (blockIdx.x / 12) * 64, eb = (blockIdx.x % 12) * 64;
  int t = threadIdx.x;
  int r = t >> 2, c0 = (t & 3) * 16;
  #pragma unroll
  for (int j = 0; j < 4; j++) {
    f32x4 v = *(const f32x4*)(w1 + (kb + r)*ND + eb + c0 + j*4);
    *(f32x4*)&tile[r][c0 + j*4] = v;
  }
  __syncthreads();
  int e = t & 63, gi = t >> 6;
  int eg = eb + e;
  #pragma unroll
  for (int g2 = 0; g2 < 2; g2++) {
    int g = gi*2 + g2;
    bf16x8 o;
    #pragma unroll
    for (int j = 0; j < 8; j++) o[j] = (__bf16)tile[g*8 + j][e];
    int G = (kb >> 3) + (g ^ (eg & 7));        // bank swizzle for k3's frag reads
    *(bf16x8*)(w1t + eg*ND + G*8) = o;
  }
}

// split f32x4 into truncated-bf16 hi (packed pair uints) and exact-remainder
// lo (truncated to bf16); accumulate sum of squares of the f32 values.
__device__ __forceinline__ void cvt4(f32x4 v, unsigned& hp0, unsigned& hp1,
                                     unsigned& lp0, unsigned& lp1, float& sq) {
  unsigned u0 = __float_as_uint(v[0]), u1 = __float_as_uint(v[1]);
  unsigned u2 = __float_as_uint(v[2]), u3 = __float_as_uint(v[3]);
  hp0 = (u1 & 0xffff0000u) | (u0 >> 16);
  hp1 = (u3 & 0xffff0000u) | (u2 >> 16);
  float l0 = v[0] - __uint_as_float(u0 & 0xffff0000u);   // exact (Sterbenz)
  float l1 = v[1] - __uint_as_float(u1 & 0xffff0000u);
  float l2 = v[2] - __uint_as_float(u2 & 0xffff0000u);
  float l3 = v[3] - __uint_as_float(u3 & 0xffff0000u);
  lp0 = (__float_as_uint(l1) & 0xffff0000u) | (__float_as_uint(l0) >> 16);
  lp1 = (__float_as_uint(l3) & 0xffff0000u) | (__float_as_uint(l2) >> 16);
  sq += v[0]*v[0] + v[1]*v[1] + v[2]*v[2] + v[3]*v[3];
}

// ---------------- K2a v2: cosine screen with 2-blocks/CU overlap -----------
// Best-measured screen variant (round 6). Block = (bk, half): 64 ctx rows x
// 128 ent, grid 512, 256 thr = 4 waves, LDS 72.5 KB -> 2 blocks/CU. The
// bk-pair is mapped 256 apart in blockIdx -> same XCD (round-robin mod 8),
// lockstep kt -> duplicated ent-tile reads hit L2 (HBM stays ~201 MB).
// NOTE (r0/r3/r6 probes): time is invariant to padding, occupancy split, and
// block shape — the kernel is latency/issue-bound on the staging chain, not
// BW/LDS/conflict-bound. Left as measured-best.
__global__ __launch_bounds__(256) void k2a_screen(
    const float* __restrict__ ctxall, float* __restrict__ norm,
    int* __restrict__ amax, unsigned* __restrict__ cntg,
    unsigned* __restrict__ list) {
  __shared__ alignas(16) __bf16 Ah[2][64*32], Al[2][64*32];     // ctx hi/lo
  __shared__ alignas(16) __bf16 Bh[2][128*BTS], Bl[2][128*BTS]; // ent hi/lo
  __shared__ float einv_s[128];
  int bk = blockIdx.x & 255, half = blockIdx.x >> 8;
  int t = threadIdx.x;
  int w = t >> 6, lane = t & 63, quad = lane >> 4, eloc = lane & 15;
  bool hasA = (t < 128);                       // waves 0-1: A+B staging; 2-3: B only
  int srow = t >> 1, kh = (t & 1) * 16;
  const float* asrc = ctxall + bk*2*LD2 + (half*64 + srow)*ND + kh;
  const float* bsrc = ctxall + bk*2*LD2 + LD2 + srow*ND + kh;

  f32x4 pa[4], pb[4];
  #pragma unroll
  for (int i = 0; i < 4; i++) pb[i] = *(const f32x4*)(bsrc + i*4);
  if (hasA) {
    #pragma unroll
    for (int i = 0; i < 4; i++) pa[i] = *(const f32x4*)(asrc + i*4);
  }
  float sqa = 0.f, sqb = 0.f;
  f32x4 acc[8];
  #pragma unroll
  for (int ct = 0; ct < 8; ct++) acc[ct] = (f32x4){0,0,0,0};

  int p = 0;
  for (int kt = 0; kt < 24; kt++) {
    unsigned h0,h1,h2,h3, l0,l1,l2,l3;
    // ent staging (all threads)
    cvt4(pb[0], h0, h1, l0, l1, sqb);
    cvt4(pb[1], h2, h3, l2, l3, sqb);
    *(uint4*)&Bh[p][srow*BTS + kh] = make_uint4(h0,h1,h2,h3);
    *(uint4*)&Bl[p][srow*BTS + kh] = make_uint4(l0,l1,l2,l3);
    cvt4(pb[2], h0, h1, l0, l1, sqb);
    cvt4(pb[3], h2, h3, l2, l3, sqb);
    *((uint4*)&Bh[p][srow*BTS + kh] + 1) = make_uint4(h0,h1,h2,h3);
    *((uint4*)&Bl[p][srow*BTS + kh] + 1) = make_uint4(l0,l1,l2,l3);
    // ctx staging (waves 0-1)
    if (hasA) {
      cvt4(pa[0], h0, h1, l0, l1, sqa);
      cvt4(pa[1], h2, h3, l2, l3, sqa);
      *(uint4*)&Ah[p][srow*32 + kh] = make_uint4(h0,h1,h2,h3);
      *(uint4*)&Al[p][srow*32 + kh] = make_uint4(l0,l1,l2,l3);
      cvt4(pa[2], h0, h1, l0, l1, sqa);
      cvt4(pa[3], h2, h3, l2, l3, sqa);
      *((uint4*)&Ah[p][srow*32 + kh] + 1) = make_uint4(h0,h1,h2,h3);
      *((uint4*)&Al[p][srow*32 + kh] + 1) = make_uint4(l0,l1,l2,l3);
    }
    __syncthreads();
    if (kt < 23) {                             // prefetch next Kt over compute
      const float* b2 = bsrc + (kt+1)*32;
      #pragma unroll
      for (int i = 0; i < 4; i++) pb[i] = *(const f32x4*)(b2 + i*4);
      if (hasA) {
        const float* a2 = asrc + (kt+1)*32;
        #pragma unroll
        for (int i = 0; i < 4; i++) pa[i] = *(const f32x4*)(a2 + i*4);
      }
    }
    // compute: wave w owns ctx rows w*16..+15 (of this block's 64), all 128 ents
    bf16x8 ah = *(const bf16x8*)&Ah[p][(w*16+eloc)*32 + quad*8];
    bf16x8 al = *(const bf16x8*)&Al[p][(w*16+eloc)*32 + quad*8];
    #pragma unroll
    for (int ct = 0; ct < 8; ct++) {
      bf16x8 bh = *(const bf16x8*)&Bh[p][(ct*16+eloc)*BTS + quad*8];
      bf16x8 bl = *(const bf16x8*)&Bl[p][(ct*16+eloc)*BTS + quad*8];
      acc[ct] = __builtin_amdgcn_mfma_f32_16x16x32_bf16(al, bh, acc[ct], 0, 0, 0);
      acc[ct] = __builtin_amdgcn_mfma_f32_16x16x32_bf16(ah, bl, acc[ct], 0, 0, 0);
      acc[ct] = __builtin_amdgcn_mfma_f32_16x16x32_bf16(ah, bh, acc[ct], 0, 0, 0);
    }
    p ^= 1;
  }

  // norms: thread pair (t, t^1) holds the two k-halves of one staged row
  float stb = sqb + __shfl_xor(sqb, 1);
  if ((t & 1) == 0) {
    float n = sqrtf(stb);
    norm[NROW + bk*NL + srow] = n;             // both halves write same value (benign)
    einv_s[srow] = 1.0f / n;
  }
  if (hasA) {
    float sta = sqa + __shfl_xor(sqa, 1);
    if ((t & 1) == 0) norm[bk*NL + half*64 + srow] = sqrtf(sta);
  }
  __syncthreads();

  // epilogue: per-row argmax of acc*einv + theta-window candidate push
  #pragma unroll
  for (int rr = 0; rr < 4; rr++) {
    float sc[8];
    float best = -3.0e38f; int bcol = 0;
    #pragma unroll
    for (int ct = 0; ct < 8; ct++) {
      sc[ct] = acc[ct][rr] * einv_s[ct*16 + eloc];
      int col = ct*16 + eloc;
      if (sc[ct] > best) { best = sc[ct]; bcol = col; }
    }
    #pragma unroll
    for (int m = 1; m < 16; m <<= 1) {
      float ov = __shfl_xor(best, m);
      int   oc = __shfl_xor(bcol, m);
      if (ov > best || (ov == best && oc < bcol)) { best = ov; bcol = oc; }
    }
    int grow = bk*NL + half*64 + w*16 + quad*4 + rr;
    if (eloc == 0) amax[grow] = bcol;
    int cnt = 0;
    #pragma unroll
    for (int ct = 0; ct < 8; ct++) cnt += (sc[ct] >= best - THETA) ? 1 : 0;
    #pragma unroll
    for (int m = 1; m < 16; m <<= 1) cnt += __shfl_xor(cnt, m);
    if (cnt >= 2) {                            // near-tie: exact rescore needed
      #pragma unroll
      for (int ct = 0; ct < 8; ct++) {
        if (sc[ct] >= best - THETA) {
          unsigned idx = atomicAdd(cntg, 1u);
          if (idx < CAP) list[idx] = ((unsigned)grow << 7) | (unsigned)(ct*16 + eloc);
        }
      }
    }
  }
}

// ---------------- K2b: exact f32 rescore of near-tie candidates ------------
__global__ __launch_bounds__(256) void k2b_rescore(
    const float* __restrict__ ctxall, const float* __restrict__ norm,
    const unsigned* __restrict__ cntg, const unsigned* __restrict__ list,
    unsigned long long* __restrict__ amax2) {
  unsigned n = *cntg; if (n > CAP) n = CAP;
  int lane = threadIdx.x & 63;
  unsigned wv = blockIdx.x*4 + (threadIdx.x >> 6);
  for (unsigned e = wv; e < n; e += 256) {
    unsigned ent = list[e];
    int row = (int)(ent >> 7), col = (int)(ent & 127);
    int bk = row >> 7;
    const float* a = ctxall + row_off(row);
    const float* b = ctxall + bk*2*LD2 + LD2 + col*ND;
    float d = 0.f;
    #pragma unroll
    for (int i = 0; i < 3; i++) {
      f32x4 va = *(const f32x4*)(a + lane*12 + i*4);
      f32x4 vb = *(const f32x4*)(b + lane*12 + i*4);
      d += va[0]*vb[0] + va[1]*vb[1] + va[2]*vb[2] + va[3]*vb[3];
    }
    #pragma unroll
    for (int m = 1; m < 64; m <<= 1) d += __shfl_xor(d, m);
    if (lane == 0) {
      float cn = norm[row], en = norm[NROW + bk*NL + col];
      float s = d / (cn*en + EPSF);
      unsigned su = __float_as_uint(s);
      unsigned ord = (su & 0x80000000u) ? ~su : (su | 0x80000000u);
      unsigned long long key = ((unsigned long long)ord << 32) | (unsigned)(127 - col);
      atomicMax(&amax2[row], key);
    }
  }
}

// ---------------- K3: fused MLP per row (round-0 version, 77 us) -----------
// Measured best of all MLP variants (f32-source + cvt beats bf16-mirror 77 vs
// 123/144; fused-into-screen costs +72 on the barrier path). ~68% LDS-pipe
// occupancy (each wave streams all of w1t); the only further lever is
// 4-row-set amortization, blocked by the 256-AGPR/wave ceiling (afrag would
// need 384 accum regs -> spill, measured +120 us in round 1's spill).
__global__ __launch_bounds__(256, 2) void k3_mlp(
    const float* __restrict__ ctxall, const float* __restrict__ norm,
    const __bf16* __restrict__ w1t, const float* __restrict__ b1,
    const float* __restrict__ w2, float* __restrict__ val) {
  __shared__ alignas(16) __bf16 btile[2][16*768];   // 2 x 24 KB w1t tiles
  int tid = threadIdx.x;
  int wave = tid >> 6, lane = tid & 63;
  int quad = lane >> 4, eloc = lane & 15;
  int rbase = blockIdx.x*128 + wave*32;

  #pragma unroll
  for (int i = 0; i < 6; i++) {
    __builtin_amdgcn_global_load_lds(
      (const __attribute__((address_space(1))) unsigned int*)(w1t + (i*256 + tid)*8),
      (__attribute__((address_space(3))) unsigned int*)(&btile[0][0] + (i*256 + tid)*8),
      16, 0, 0);
  }

  bf16x8 afrag[2][24];
  #pragma unroll
  for (int s = 0; s < 2; s++) {
    int r = rbase + s*16 + eloc;
    const float* src = ctxall + row_off(r);
    float rinv = 1.0f / norm[r];
    #pragma unroll
    for (int ks = 0; ks < 24; ks++) {
      const float* sp = src + ks*32 + quad*8;
      f32x4 v0 = *(const f32x4*)sp;
      f32x4 v1 = *(const f32x4*)(sp + 4);
      bf16x8 a;
      a[0] = (__bf16)(v0[0]*rinv); a[1] = (__bf16)(v0[1]*rinv);
      a[2] = (__bf16)(v0[2]*rinv); a[3] = (__bf16)(v0[3]*rinv);
      a[4] = (__bf16)(v1[0]*rinv); a[5] = (__bf16)(v1[1]*rinv);
      a[6] = (__bf16)(v1[2]*rinv); a[7] = (__bf16)(v1[3]*rinv);
      afrag[s][ks] = a;
    }
  }

  float oacc[2][4] = {{0,0,0,0},{0,0,0,0}};
  int p = 0;
  for (int nt = 0; nt < 48; nt++) {
    __syncthreads();
    if (nt < 47) {
      const __bf16* gsrc = w1t + (nt+1)*16*ND;
      #pragma unroll
      for (int i = 0; i < 6; i++) {
        __builtin_amdgcn_global_load_lds(
          (const __attribute__((address_space(1))) unsigned int*)(gsrc + (i*256 + tid)*8),
          (__attribute__((address_space(3))) unsigned int*)(&btile[p^1][0] + (i*256 + tid)*8),
          16, 0, 0);
      }
    }
    f32x4 h0 = {0,0,0,0}, h1 = {0,0,0,0};
    #pragma unroll
    for (int ks = 0; ks < 24; ks++) {
      int g = ks*4 + quad;
      bf16x8 bfrag = *(const bf16x8*)(&btile[p][0] + eloc*ND + ((g ^ (eloc & 7))*8));
      h0 = __builtin_amdgcn_mfma_f32_16x16x32_bf16(afrag[0][ks], bfrag, h0, 0, 0, 0);
      h1 = __builtin_amdgcn_mfma_f32_16x16x32_bf16(afrag[1][ks], bfrag, h1, 0, 0, 0);
    }
    float b1v = b1[nt*16 + eloc];
    float w2v = w2[nt*16 + eloc];
    #pragma unroll
    for (int rr = 0; rr < 4; rr++) {
      oacc[0][rr] += fmaxf(h0[rr] + b1v, 0.f) * w2v;
      oacc[1][rr] += fmaxf(h1[rr] + b1v, 0.f) * w2v;
    }
    p ^= 1;
  }
  #pragma unroll
  for (int m = 1; m < 16; m <<= 1)
    #pragma unroll
    for (int s = 0; s < 2; s++)
      #pragma unroll
      for (int rr = 0; rr < 4; rr++)
        oacc[s][rr] += __shfl_xor(oacc[s][rr], m);
  if (eloc == 0) {
    #pragma unroll
    for (int s = 0; s < 2; s++)
      #pragma unroll
      for (int rr = 0; rr < 4; rr++)
        val[rbase + s*16 + quad*4 + rr] = oacc[s][rr];
  }
}

// ---------------- K4: gather-add final output (with fixup override) --------
__global__ void k4_out(const float* __restrict__ val, const int* __restrict__ amax,
                       const unsigned long long* __restrict__ amax2,
                       const float* __restrict__ b2, float* __restrict__ out) {
  int i = blockIdx.x*256 + threadIdx.x;      // < NROW
  int bk = i >> 7;
  unsigned long long k = amax2[i];
  int a = k ? (127 - (int)(k & 127ull)) : amax[i];
  out[i] = val[i] + val[NROW + bk*NL + a] + 2.0f*b2[0];
}

extern "C" void kernel_launch(void* const* d_in, const int* in_sizes, int n_in,
                              void* d_out, int out_size, void* d_ws, size_t ws_size,
                              hipStream_t stream) {
  const float* ctxall = (const float*)d_in[0];
  const float* w1 = (const float*)d_in[1];
  const float* b1 = (const float*)d_in[2];
  const float* w2 = (const float*)d_in[3];
  const float* b2 = (const float*)d_in[4];
  float* out = (float*)d_out;

  char* ws = (char*)d_ws;
  float*    norm = (float*)ws;                        // [0, 262144)
  int*      amax = (int*)(ws + 262144);               // [262144, 393216)
  float*    val  = (float*)(ws + 393216);             // [393216, 655360)
  __bf16*   w1t  = (__bf16*)(ws + 655360);            // [655360, 1835008)
  unsigned long long* amax2 = (unsigned long long*)(ws + 1835008);  // 256 KB
  unsigned* cntg = (unsigned*)(ws + 2097152);         // 4 B
  unsigned* list = (unsigned*)(ws + 2097156);         // 64 KB

  hipLaunchKernelGGL(k0_w1t,     dim3(144),        dim3(256), 0, stream, w1, w1t, amax2, cntg);
  hipLaunchKernelGGL(k2a_screen, dim3(2*NBK),      dim3(256), 0, stream, ctxall, norm, amax, cntg, list);
  hipLaunchKernelGGL(k2b_rescore,dim3(64),         dim3(256), 0, stream, ctxall, norm, cntg, list, amax2);
  hipLaunchKernelGGL(k3_mlp,     dim3(2*NROW/128), dim3(256), 0, stream, ctxall, norm, w1t, b1, w2, val);
  hipLaunchKernelGGL(k4_out,     dim3(NROW/256),   dim3(256), 0, stream, val, amax, amax2, b2, out);
}